// Round 9
// baseline (314.140 us; speedup 1.0000x reference)
//
#include <hip/hip_runtime.h>
#include <hip/hip_bf16.h>

// QuantizedLinear: out[M,N] = inp[M,K] @ (qw[N,K] * scale[N])^T
// M = 4096, K = 4096, N = 12288.
// INT8 path:
//   Pass 1a: per-row absmax-quantize A fp32 -> int8 (+ row scale Ra[m]).
//   Pass 1b: W int32 -> int8 (exact).
//   Pass 2:  256x256 8-wave i8 GEMM, mfma_i32_16x16x64_i8, BK=128 bytes,
//            TWO phases per K-tile (was 4): halves barrier/drain overhead,
//            round-4 staging cadence preserved exactly. T1 XCD swizzle,
//            T2 both-sides XOR swizzle, T5 setprio, global_load_lds w=16.
//   Epilogue: out = (float)acc * scale_w[col] * Ra[row].

#define K_DIM 4096
#define N_DIM 12288

constexpr int BM = 256;
constexpr int BN = 256;
constexpr int BKB = 128;          // K-tile in elements == bytes (i8)
constexpr int NT = K_DIM / BKB;   // 32

typedef float  f32x4  __attribute__((ext_vector_type(4)));
typedef int    i32x4  __attribute__((ext_vector_type(4)));
typedef short  bf16x8 __attribute__((ext_vector_type(8)));
typedef unsigned short u16x4 __attribute__((ext_vector_type(4)));

__device__ __forceinline__ unsigned short f32_to_bf16(float f) {
    unsigned int u = __builtin_bit_cast(unsigned int, f);
    u += 0x7FFFu + ((u >> 16) & 1u);
    return (unsigned short)(u >> 16);
}

// ---------------- Pass 1a: per-row quantize A -> int8 ----------------

__global__ __launch_bounds__(256)
void quant_a_kernel(const float* __restrict__ A,
                    signed char* __restrict__ Aq,
                    float* __restrict__ Ra) {
    const int row  = blockIdx.x;
    const int tid  = threadIdx.x;
    const int lane = tid & 63;
    const int wid  = tid >> 6;
    const float* arow = A + (size_t)row * K_DIM;
    const int base = tid * 16;

    f32x4 v[4];
    #pragma unroll
    for (int i = 0; i < 4; ++i)
        v[i] = *(const f32x4*)(arow + base + i * 4);

    float mx = 0.f;
    #pragma unroll
    for (int i = 0; i < 4; ++i)
        #pragma unroll
        for (int j = 0; j < 4; ++j)
            mx = fmaxf(mx, fabsf(v[i][j]));

    #pragma unroll
    for (int off = 32; off > 0; off >>= 1)
        mx = fmaxf(mx, __shfl_xor(mx, off));

    __shared__ float wmax[4];
    if (lane == 0) wmax[wid] = mx;
    __syncthreads();
    mx = fmaxf(fmaxf(wmax[0], wmax[1]), fmaxf(wmax[2], wmax[3]));

    const float inv = (mx > 0.f) ? (127.0f / mx) : 0.f;
    if (tid == 0) Ra[row] = mx * (1.0f / 127.0f);

    int p[4];
    #pragma unroll
    for (int i = 0; i < 4; ++i) {
        int b0 = (int)rintf(v[i][0] * inv);
        int b1 = (int)rintf(v[i][1] * inv);
        int b2 = (int)rintf(v[i][2] * inv);
        int b3 = (int)rintf(v[i][3] * inv);
        p[i] = (b0 & 255) | ((b1 & 255) << 8) | ((b2 & 255) << 16) | (b3 << 24);
    }
    *(i32x4*)(Aq + (size_t)row * K_DIM + base) = *(i32x4*)p;
}

// ---------------- Pass 1b: W int32 -> int8 (exact) ----------------

__global__ __launch_bounds__(256)
void cvt_w8_kernel(const int* __restrict__ W, signed char* __restrict__ Wq, int n16) {
    int stride = gridDim.x * blockDim.x;
    for (int i = blockIdx.x * blockDim.x + threadIdx.x; i < n16; i += stride) {
        const int* src = W + (size_t)i * 16;
        int p[4];
        #pragma unroll
        for (int q = 0; q < 4; ++q) {
            const i32x4 w = *(const i32x4*)(src + q * 4);
            p[q] = (w[0] & 255) | ((w[1] & 255) << 8) | ((w[2] & 255) << 16) | (w[3] << 24);
        }
        *(i32x4*)(Wq + (size_t)i * 16) = *(i32x4*)p;
    }
}

// ---------------- Pass 2: 256^2 i8 GEMM, 2 phases per K-tile ----------------

__device__ __forceinline__ void gload_lds16(const void* g, void* l) {
    __builtin_amdgcn_global_load_lds(
        (const __attribute__((address_space(1))) unsigned int*)g,
        (__attribute__((address_space(3))) unsigned int*)l,
        16, 0, 0);
}

__global__ __launch_bounds__(512, 2)
void gemm_i8_256(const signed char* __restrict__ Aq,   // [M,K] i8
                 const signed char* __restrict__ Wq,   // [N,K] i8
                 const float* __restrict__ Sw,         // [N]
                 const float* __restrict__ Ra,         // [M]
                 float* __restrict__ Out,              // [M,N]
                 int M) {
    __shared__ __align__(16) unsigned char As8[2][BM * BKB];   // 2 x 32 KB
    __shared__ __align__(16) unsigned char Bs8[2][BN * BKB];   // 2 x 32 KB

    const int tid  = threadIdx.x;
    const int lane = tid & 63;
    const int wid  = tid >> 6;          // 0..7
    const int wm   = wid >> 2;          // 0..1  (128-row half)
    const int wn   = wid & 3;           // 0..3  (64-col strip)

    // T1: XCD swizzle (768 blocks, 96/XCD), column-major within chunk
    const int nwgy = M / BM;                 // 16
    const int nwg  = (N_DIM / BN) * nwgy;    // 768
    const int cpx  = nwg >> 3;               // 96
    const int bid  = blockIdx.x;
    const int swz  = (bid & 7) * cpx + (bid >> 3);
    const int bx   = swz / nwgy;
    const int by   = swz % nwgy;
    const int bm   = by * BM;
    const int bn   = bx * BN;

    // staging: chunk c = j*8+wid, lane writes c*1024B + lane*16B ->
    // row c*8+(lane>>3), colB (lane&7)*16. T2: pre-swizzle GLOBAL col by row&7.
    const int srow  = wid * 8 + (lane >> 3);
    const int scolB = ((lane & 7) ^ (lane >> 3)) * 16;      // bytes

    #define STG_H(G, grow0, k0B, L)                                                 \
        do {                                                                        \
            gload_lds16((G) + (size_t)((grow0) + srow) * K_DIM + (k0B) + scolB,     \
                        (L) + wid * 1024);                                          \
            gload_lds16((G) + (size_t)((grow0) + 64 + srow) * K_DIM + (k0B) + scolB,\
                        (L) + 8192 + wid * 1024);                                   \
        } while (0)

    i32x4 acc[8][4];
    #pragma unroll
    for (int i = 0; i < 8; ++i)
        #pragma unroll
        for (int j = 0; j < 4; ++j)
            acc[i][j] = (i32x4){0, 0, 0, 0};

    const int c0   = lane & 15;
    const int kgB  = (lane >> 4) * 16;     // byte offset of lane's K-group
    const int rswB = (c0 & 7) * 16;        // read-side swizzle (row&7 == c0&7)

    i32x4 af[8][2];      // 8 m-frags x 2 k-slices (each 16 i8 = 16B)
    i32x4 bf0[2][2];     // B rows wn*64 + 0..31
    i32x4 bf1[2][2];     // B rows wn*64 + 32..63

    const int aoffA = (wm * 128 + c0) * BKB;   // byte base of wave's A rows
    const int aoffB = (wn * 64 + c0) * BKB;

    #define RD_A(base, BUF, row0)                                                   \
        _Pragma("unroll") for (int mf = 0; mf < 4; ++mf)                            \
        _Pragma("unroll") for (int ks = 0; ks < 2; ++ks)                            \
            af[(base) + mf][ks] = *(const i32x4*)&As8[BUF][aoffA + ((row0) + mf * 16) * BKB + ((ks * 64 + kgB) ^ rswB)];

    #define RD_B(dst, BUF, row0)                                                    \
        _Pragma("unroll") for (int nf = 0; nf < 2; ++nf)                            \
        _Pragma("unroll") for (int ks = 0; ks < 2; ++ks)                            \
            (dst)[nf][ks] = *(const i32x4*)&Bs8[BUF][aoffB + ((row0) + nf * 16) * BKB + ((ks * 64 + kgB) ^ rswB)];

    #define CLUSTER(qm, qn, BF)                                                     \
        _Pragma("unroll") for (int ks = 0; ks < 2; ++ks)                            \
        _Pragma("unroll") for (int mf = 0; mf < 4; ++mf)                            \
        _Pragma("unroll") for (int nf = 0; nf < 2; ++nf)                            \
            acc[(qm)*4 + mf][(qn)*2 + nf] = __builtin_amdgcn_mfma_i32_16x16x64_i8(  \
                af[(qm)*4 + mf][ks], (BF)[nf][ks], acc[(qm)*4 + mf][(qn)*2 + nf],   \
                0, 0, 0);

    // ---- prologue: tile0 complete + A-halves of tile1; 4 loads stay in flight ----
    STG_H(Aq, bm,       0,   &As8[0][0]);
    STG_H(Aq, bm + 128, 0,   &As8[0][16384]);
    STG_H(Wq, bn,       0,   &Bs8[0][0]);
    STG_H(Wq, bn + 128, 0,   &Bs8[0][16384]);
    STG_H(Aq, bm,       BKB, &As8[1][0]);
    STG_H(Aq, bm + 128, BKB, &As8[1][16384]);
    asm volatile("s_waitcnt vmcnt(4)" ::: "memory");   // tile0 landed; A(1) in flight
    __builtin_amdgcn_s_barrier();

    // ---- K-loop: 2 phases per K-tile (round-4 cadence, merged).
    //   ph0: rd af0-7 + bf0 (20 reads) | STG B0,B1(t+1)->nxt
    //        bar | lgkm0 | MFMA (0,0)+(1,0) [32] | bar
    //   ph1: rd bf1 (4 reads)          | STG A0,A1(t+2)->cur
    //        bar | lgkm0 | MFMA (0,1)+(1,1) [32] | vmcnt(4) | bar
    // Hazards identical to round 4: B(t+1) -> other buffer (no readers);
    // A(t+2) -> cur issued one barrier after last A-read drained;
    // vmcnt(4) forces B(t+1)+older, leaves A(t+2) x4 in flight. ----
    for (int t = 0; t < NT; ++t) {
        const int cur = t & 1;
        unsigned char* Bnx  = &Bs8[cur ^ 1][0];   // B(t+1)
        unsigned char* Acur = &As8[cur][0];       // A(t+2)
        const int k1 = (t + 1) * BKB;
        const int k2 = (t + 2) * BKB;

        // ---- ph0 ----
        RD_A(0, cur, 0);
        RD_A(4, cur, 64);
        RD_B(bf0, cur, 0);
        if (t + 1 < NT) {
            STG_H(Wq, bn,       k1, Bnx);
            STG_H(Wq, bn + 128, k1, Bnx + 16384);
        }
        __builtin_amdgcn_s_barrier();
        asm volatile("s_waitcnt lgkmcnt(0)");
        __builtin_amdgcn_s_setprio(1);
        CLUSTER(0, 0, bf0);
        CLUSTER(1, 0, bf0);
        __builtin_amdgcn_s_setprio(0);
        __builtin_amdgcn_s_barrier();

        // ---- ph1 ----
        RD_B(bf1, cur, 32);
        if (t + 2 < NT) {
            STG_H(Aq, bm,       k2, Acur);
            STG_H(Aq, bm + 128, k2, Acur + 16384);
        }
        __builtin_amdgcn_s_barrier();
        asm volatile("s_waitcnt lgkmcnt(0)");
        __builtin_amdgcn_s_setprio(1);
        CLUSTER(0, 1, bf1);
        CLUSTER(1, 1, bf1);
        __builtin_amdgcn_s_setprio(0);
        if (t < NT - 2) {
            asm volatile("s_waitcnt vmcnt(4)" ::: "memory");
        } else if (t == NT - 2) {
            asm volatile("s_waitcnt vmcnt(0)" ::: "memory");
        }
        __builtin_amdgcn_s_barrier();
    }
    #undef CLUSTER
    #undef RD_A
    #undef RD_B
    #undef STG_H

    // ---- epilogue: C/D col = lane&15 (B idx), row = (lane>>4)*4 + j (A idx) ----
    const int r0 = (lane >> 4) * 4;
    float rav[8][4];
    #pragma unroll
    for (int m = 0; m < 8; ++m)
        #pragma unroll
        for (int j = 0; j < 4; ++j)
            rav[m][j] = Ra[bm + wm * 128 + m * 16 + r0 + j];

    #pragma unroll
    for (int n = 0; n < 4; ++n) {
        const int col = bn + wn * 64 + n * 16 + c0;
        const float s = Sw[col];
        #pragma unroll
        for (int m = 0; m < 8; ++m) {
            const int rowb = bm + wm * 128 + m * 16 + r0;
            #pragma unroll
            for (int j = 0; j < 4; ++j)
                Out[(size_t)(rowb + j) * N_DIM + col] = (float)acc[m][n][j] * s * rav[m][j];
        }
    }
}

// ---------------- Fallback (fused bf16, if ws too small) ----------------

constexpr int FBM = 128, FBN = 128, FBK = 64, FPAD = 8;

__global__ __launch_bounds__(256)
void qlinear_fused_kernel(const float* __restrict__ A, const int* __restrict__ Wqi,
                          const float* __restrict__ Sw, float* __restrict__ Out, int M) {
    __shared__ unsigned short Asf[FBM][FBK + FPAD];
    __shared__ unsigned short Bsf[FBN][FBK + FPAD];
    const int tid  = threadIdx.x;
    const int lane = tid & 63;
    const int wid  = tid >> 6;
    const int wm   = wid >> 1;
    const int wn   = wid & 1;
    const int bm = blockIdx.y * FBM;
    const int bn = blockIdx.x * FBN;
    const int rowT = tid >> 4;
    const int kq   = tid & 15;
    f32x4 acc[4][4];
    #pragma unroll
    for (int i = 0; i < 4; ++i)
        #pragma unroll
        for (int j = 0; j < 4; ++j) acc[i][j] = (f32x4){0.f,0.f,0.f,0.f};
    const int c0 = lane & 15;
    const int kg = (lane >> 4) * 8;
    for (int k0 = 0; k0 < K_DIM; k0 += FBK) {
        #pragma unroll
        for (int it = 0; it < 8; ++it) {
            const int r = it * 16 + rowT;
            const f32x4 a4 = *(const f32x4*)(A + (size_t)(bm + r) * K_DIM + k0 + kq * 4);
            u16x4 h;
            h[0]=f32_to_bf16(a4[0]); h[1]=f32_to_bf16(a4[1]);
            h[2]=f32_to_bf16(a4[2]); h[3]=f32_to_bf16(a4[3]);
            *(u16x4*)&Asf[r][kq*4] = h;
        }
        #pragma unroll
        for (int it = 0; it < 8; ++it) {
            const int r = it * 16 + rowT;
            const i32x4 w4 = *(const i32x4*)(Wqi + (size_t)(bm + 0) * 0 + (size_t)(bn + r) * K_DIM + k0 + kq * 4);
            u16x4 h;
            h[0]=f32_to_bf16((float)w4[0]); h[1]=f32_to_bf16((float)w4[1]);
            h[2]=f32_to_bf16((float)w4[2]); h[3]=f32_to_bf16((float)w4[3]);
            *(u16x4*)&Bsf[r][kq*4] = h;
        }
        __syncthreads();
        #pragma unroll
        for (int ks = 0; ks < 2; ++ks) {
            const int kk = ks * 32 + kg;
            bf16x8 af2[4], bfr[4];
            #pragma unroll
            for (int mf = 0; mf < 4; ++mf)
                af2[mf] = *(const bf16x8*)&Asf[wm*64 + mf*16 + c0][kk];
            #pragma unroll
            for (int nf = 0; nf < 4; ++nf)
                bfr[nf] = *(const bf16x8*)&Bsf[wn*64 + nf*16 + c0][kk];
            #pragma unroll
            for (int mf = 0; mf < 4; ++mf)
                #pragma unroll
                for (int nf = 0; nf < 4; ++nf)
                    acc[mf][nf] = __builtin_amdgcn_mfma_f32_16x16x32_bf16(
                        af2[mf], bfr[nf], acc[mf][nf], 0, 0, 0);
        }
        __syncthreads();
    }
    const int r0 = (lane >> 4) * 4;
    #pragma unroll
    for (int nf = 0; nf < 4; ++nf) {
        const int col = bn + wn*64 + nf*16 + c0;
        const float s = Sw[col];
        #pragma unroll
        for (int mf = 0; mf < 4; ++mf) {
            const int rowb = bm + wm*64 + mf*16 + r0;
            #pragma unroll
            for (int j = 0; j < 4; ++j)
                Out[(size_t)(rowb + j) * N_DIM + col] = acc[mf][nf][j] * s;
        }
    }
}

extern "C" void kernel_launch(void* const* d_in, const int* in_sizes, int n_in,
                              void* d_out, int out_size, void* d_ws, size_t ws_size,
                              hipStream_t stream) {
    const float* inp = (const float*)d_in[0];
    const int*   qw  = (const int*)d_in[1];
    const float* sw  = (const float*)d_in[2];
    float*       out = (float*)d_out;

    const int M = in_sizes[0] / K_DIM;                         // 4096
    const size_t nA = (size_t)M * K_DIM;                       // A elements
    const size_t nW = (size_t)N_DIM * K_DIM;                   // W elements
    const size_t needQ = nA + nW + (size_t)M * sizeof(float);  // ~67 MiB

    if (ws_size >= needQ && (M % BM) == 0) {
        signed char* Aq = (signed char*)d_ws;
        signed char* Wq8 = Aq + nA;
        float*       Ra = (float*)(Wq8 + nW);
        quant_a_kernel<<<M, 256, 0, stream>>>(inp, Aq, Ra);
        cvt_w8_kernel<<<2048, 256, 0, stream>>>(qw, Wq8, (int)(nW / 16));
        dim3 grid((N_DIM / BN) * (M / BM));                    // 768
        gemm_i8_256<<<grid, 512, 0, stream>>>(Aq, Wq8, sw, Ra, out, M);
    } else {
        dim3 grid(N_DIM / FBN, M / FBM);
        qlinear_fused_kernel<<<grid, 256, 0, stream>>>(inp, qw, sw, out, M);
    }
}